// Round 1
// baseline (153.729 us; speedup 1.0000x reference)
//
#include <hip/hip_runtime.h>
#include <hip/hip_bf16.h>

typedef float f32x4 __attribute__((ext_vector_type(4)));
typedef __bf16 bf16x8 __attribute__((ext_vector_type(8)));
typedef unsigned short ushort8 __attribute__((ext_vector_type(8)));

constexpr int kB = 2048;
constexpr int kF = 40;
constexpr int kD = 64;
constexpr int kP = 780;            // 40*39/2
constexpr int kFD = kF * kD;       // 2560
constexpr int BT = 512;            // batch rows per block
constexpr int NBT = kB / BT;       // 4
constexpr int NBLK = kP * NBT;     // 3120 blocks
constexpr int PASSES = BT / 64;    // 8 (4 waves x 16 rows each per pass)

__device__ __forceinline__ unsigned short f2bf_bits(float f) {
  unsigned u = __builtin_bit_cast(unsigned, f);
  u += 0x7FFFu + ((u >> 16) & 1u);
  return (unsigned short)(u >> 16);
}

__global__ __launch_bounds__(256) void bilinear_main(
    const float* __restrict__ x, const float* __restrict__ W,
    float* __restrict__ out) {
  // XCD-bijective decode: 3120 = 8 chunks of 390; within a chunk, btile fastest,
  // so each XCD owns ~98 consecutive p values (L2 write-merge for out columns).
  const int gid = blockIdx.x;
  const int xcd = gid & 7;
  const int g = gid >> 3;
  const int item = xcd * (NBLK / 8) + g;   // NBLK/8 = 390
  const int p = item >> 2;                 // NBT == 4
  const int btile = item & 3;

  // decode pair (i_f, j_f) from p  (triu_indices order, k=1)
  int i_f = 0, s = 0;
  while (s + (kF - 1 - i_f) <= p) { s += kF - 1 - i_f; ++i_f; }
  const int j_f = i_f + 1 + (p - s);

  const int lane = threadIdx.x & 63;
  const int wave = threadIdx.x >> 6;
  const int lo = lane & 15;
  const int hi = lane >> 4;

  // --- B fragments: W[p][k][e]; frag(kk,nb): k = kk*32 + hi*8 + t, e = nb*16 + lo
  // Loaded once per block, reused for all 8 passes (64 MFMAs/wave).
  const float* wp = W + (size_t)p * (kD * kD);
  bf16x8 bfrag[2][4];
#pragma unroll
  for (int kk = 0; kk < 2; ++kk) {
#pragma unroll
    for (int nb = 0; nb < 4; ++nb) {
      ushort8 tmp;
#pragma unroll
      for (int t = 0; t < 8; ++t)
        tmp[t] = f2bf_bits(wp[(kk * 32 + hi * 8 + t) * kD + nb * 16 + lo]);
      bfrag[kk][nb] = __builtin_bit_cast(bf16x8, tmp);
    }
  }

  const int b0 = btile * BT;
  for (int pass = 0; pass < PASSES; ++pass) {
    const int rb = b0 + pass * 64 + wave * 16;

    // --- A fragments from x_i: row = lane&15, k = kk*32 + hi*8 + t
    const float* xi = x + (size_t)(rb + lo) * kFD + i_f * kD;
    bf16x8 afrag[2];
#pragma unroll
    for (int kk = 0; kk < 2; ++kk) {
      f32x4 v0 = *(const f32x4*)(xi + kk * 32 + hi * 8);
      f32x4 v1 = *(const f32x4*)(xi + kk * 32 + hi * 8 + 4);
      ushort8 tmp;
#pragma unroll
      for (int t = 0; t < 4; ++t) {
        tmp[t] = f2bf_bits(v0[t]);
        tmp[t + 4] = f2bf_bits(v1[t]);
      }
      afrag[kk] = __builtin_bit_cast(bf16x8, tmp);
    }

    // --- MFMA: Y[16 rows][64 e] for this row tile
    f32x4 acc[4];
#pragma unroll
    for (int nb = 0; nb < 4; ++nb) acc[nb] = f32x4{0.f, 0.f, 0.f, 0.f};
#pragma unroll
    for (int kk = 0; kk < 2; ++kk) {
#pragma unroll
      for (int nb = 0; nb < 4; ++nb)
        acc[nb] = __builtin_amdgcn_mfma_f32_16x16x32_bf16(
            afrag[kk], bfrag[kk][nb], acc[nb], 0, 0, 0);
    }

    // --- epilogue: out[b,p] = sum_e Y[b][e] * x[b, j_f, e]
    // C/D layout: col = lane&15 (+16*nb), row = hi*4 + q  [m89-verified]
#pragma unroll
    for (int q = 0; q < 4; ++q) {
      const int row = rb + hi * 4 + q;
      const float* xj = x + (size_t)row * kFD + j_f * kD + lo;
      float sum = 0.f;
#pragma unroll
      for (int nb = 0; nb < 4; ++nb) sum += acc[nb][q] * xj[nb * 16];
      sum += __shfl_xor(sum, 1, 64);
      sum += __shfl_xor(sum, 2, 64);
      sum += __shfl_xor(sum, 4, 64);
      sum += __shfl_xor(sum, 8, 64);
      if (lo == 0) out[(size_t)row * kP + p] = sum;
    }
  }
}

extern "C" void kernel_launch(void* const* d_in, const int* in_sizes, int n_in,
                              void* d_out, int out_size, void* d_ws, size_t ws_size,
                              hipStream_t stream) {
  const float* x = (const float*)d_in[0];
  const float* W = (const float*)d_in[1];
  float* out = (float*)d_out;
  hipLaunchKernelGGL(bilinear_main, dim3(NBLK), dim3(256), 0, stream, x, W, out);
}